// Round 3
// baseline (39278.992 us; speedup 1.0000x reference)
//
#include <hip/hip_runtime.h>
#include <hip/hip_fp16.h>

// Problem constants: B=256, T=256, M=512, P=512
typedef _Float16 h4 __attribute__((ext_vector_type(4)));
typedef _Float16 h8 __attribute__((ext_vector_type(8)));
typedef float    f4 __attribute__((ext_vector_type(4)));

#define SC2LOG2E 2.8853900817779268f   // 2 * log2(e)

__device__ __forceinline__ float v_exp2(float x) { float r; asm("v_exp_f32 %0, %1" : "=v"(r) : "v"(x)); return r; }
__device__ __forceinline__ float v_rcp (float x) { float r; asm("v_rcp_f32 %0, %1" : "=v"(r) : "v"(x)); return r; }
__device__ __forceinline__ float fast_tanh(float x) {
    float e = __expf(2.0f * x);
    return 1.0f - 2.0f * v_rcp(e + 1.0f);
}
__device__ __forceinline__ float fast_sigmoid(float x) {
    return v_rcp(1.0f + __expf(-x));
}

// ---------------------------------------------------------------------------
__global__ void convert_f16(const float* __restrict__ s, _Float16* __restrict__ d, int n) {
    int i = (blockIdx.x * 256 + threadIdx.x) * 4;
    if (i < n) {
        float4 v = *(const float4*)(s + i);
        h4 o = {(_Float16)v.x, (_Float16)v.y, (_Float16)v.z, (_Float16)v.w};
        *(h4*)(d + i) = o;
    }
}

// H f32 -> Hh half of combined buffer: CB row r (stride 1024 f16) = [UH2|Hh]
__global__ void convert_cb(const float* __restrict__ H, _Float16* __restrict__ CB) {
    int i = (blockIdx.x * 256 + threadIdx.x) * 4;   // over 33554432
    int r = i >> 9, m = i & 511;
    float4 v = *(const float4*)(H + i);
    h4 o = {(_Float16)v.x, (_Float16)v.y, (_Float16)v.z, (_Float16)v.w};
    *(h4*)(CB + (size_t)r * 1024 + 512 + m) = o;
}

// ---------------------------------------------------------------------------
// Wg[(p<<2)|g][k] = f16( k<512 ? Wih[g*512+p][k] : Whh[g*512+p][k-512] )
__global__ void build_wg(const float* __restrict__ Wih, const float* __restrict__ Whh,
                         _Float16* __restrict__ Wg) {
    int idx = (blockIdx.x * 256 + threadIdx.x) * 4;    // over 2048*1024
    int np = idx >> 10, k = idx & 1023;
    int p = np >> 2, g = np & 3, row = g * 512 + p;
    const float* src = (k < 512) ? Wih + (size_t)row * 512 + k
                                 : Whh + (size_t)row * 512 + (k - 512);
    float4 v = *(const float4*)src;
    h4 o = {(_Float16)v.x, (_Float16)v.y, (_Float16)v.z, (_Float16)v.w};
    *(h4*)(Wg + idx) = o;
}

__global__ void build_bsum(const float* __restrict__ bih, const float* __restrict__ bhh,
                           float* __restrict__ bsum) {
    int np = blockIdx.x * 256 + threadIdx.x;  // 2048
    int p = np >> 2, g = np & 3, row = g * 512 + p;
    bsum[np] = bih[row] + bhh[row];
}

// ---------------------------------------------------------------------------
__global__ void init_state(const float* __restrict__ d0, const float* __restrict__ s0,
                           float* __restrict__ sbuf,
                           _Float16* __restrict__ qA, _Float16* __restrict__ ds) {
    int i = blockIdx.x * 256 + threadIdx.x;   // 512 x 256 = 131072
    float dv = d0[i], sv = s0[i];
    sbuf[i] = sv;
    int b = i >> 9, j = i & 511;
    qA[(size_t)b * 1024 + 512 + j] = (_Float16)dv;
    ds[(size_t)b * 1024 + j]       = (_Float16)dv;
    ds[(size_t)b * 1024 + 512 + j] = (_Float16)sv;
}

__global__ void zero_bar(unsigned* __restrict__ bar, int n) {
    int i = blockIdx.x * 256 + threadIdx.x;
    if (i < n) bar[i] = 0u;
}

// ---------------------------------------------------------------------------
// CB[r][n] (n<512, row stride 1024) = f16( 2log2e * sum_k H[r,k]*Ud[n,k] ).
// grid (1024 m-tiles of 64, 16 n-tiles of 32), 128 threads (2 waves).
__global__ __launch_bounds__(128) void uh_mfma(const float* __restrict__ H,
                                               const float* __restrict__ Ud,
                                               _Float16* __restrict__ CB) {
    int tid = threadIdx.x;
    int lane = tid & 63, w = tid >> 6;
    int ln = lane & 15, quad = lane >> 4;
    int m0 = blockIdx.x * 64, n0 = blockIdx.y * 32;
    f4 z = {0.f, 0.f, 0.f, 0.f};
    f4 acc[4] = {z, z, z, z};
    const float* brow = Ud + (size_t)(n0 + w * 16 + ln) * 512 + quad * 8;
    const float* arow = H  + (size_t)(m0 + ln) * 512 + quad * 8;
#pragma unroll 2
    for (int k = 0; k < 16; k++) {
        float4 bx = *(const float4*)(brow + k * 32);
        float4 by = *(const float4*)(brow + k * 32 + 4);
        h8 b = {(_Float16)bx.x, (_Float16)bx.y, (_Float16)bx.z, (_Float16)bx.w,
                (_Float16)by.x, (_Float16)by.y, (_Float16)by.z, (_Float16)by.w};
#pragma unroll
        for (int mt = 0; mt < 4; mt++) {
            const float* ap = arow + (size_t)mt * 16 * 512 + k * 32;
            float4 ax = *(const float4*)ap;
            float4 ay = *(const float4*)(ap + 4);
            h8 a = {(_Float16)ax.x, (_Float16)ax.y, (_Float16)ax.z, (_Float16)ax.w,
                    (_Float16)ay.x, (_Float16)ay.y, (_Float16)ay.z, (_Float16)ay.w};
            acc[mt] = __builtin_amdgcn_mfma_f32_16x16x32_f16(a, b, acc[mt], 0, 0, 0);
        }
    }
#pragma unroll
    for (int mt = 0; mt < 4; mt++)
#pragma unroll
        for (int r = 0; r < 4; r++)
            CB[(size_t)(m0 + mt * 16 + quad * 4 + r) * 1024 + n0 + w * 16 + ln] =
                (_Float16)(acc[mt][r] * SC2LOG2E);
}

// ---------------------------------------------------------------------------
// Distributed grid barrier: block bid release-stores flags[bid]=ticket; thread
// i<256 polls flags[i]; one acquire fence. Tickets monotonic per launch; flags
// zeroed by zero_bar each kernel_launch (graph-replay safe).
__device__ __forceinline__ void gbar(unsigned* __restrict__ flags, unsigned ticket) {
    __syncthreads();
    if (threadIdx.x == 0)
        __hip_atomic_store(flags + blockIdx.x, ticket, __ATOMIC_RELEASE,
                           __HIP_MEMORY_SCOPE_AGENT);
    if (threadIdx.x < 256) {
        while (__hip_atomic_load(flags + threadIdx.x, __ATOMIC_RELAXED,
                                 __HIP_MEMORY_SCOPE_AGENT) < ticket)
            __builtin_amdgcn_s_sleep(1);
    }
    __builtin_amdgcn_fence(__ATOMIC_ACQUIRE, "agent");
    __syncthreads();
}

// ---------------------------------------------------------------------------
struct LoopArgs {
    const _Float16* CB;    // [65536][1024] f16: [.,0:512]=UH2*2log2e, [.,512:1024]=Hh
    const _Float16* Wdh;
    const _Float16* Wg;
    const float*    bsum;
    const float*    vd;
    float*          wq2;
    _Float16*       qA;
    _Float16*       qB;
    _Float16*       ds;
    float*          sbuf;
    float*          out;
    float*          attn;
    unsigned*       flags;
};

// Persistent fused t-loop: 256 blocks x 1024 threads (16 waves).
// Per step: A) wq MFMA (blocks 0..127, tid<256)
//           B) fused online-softmax attention (block b = batch b, all 16 waves)
//           C) gates MFMA + LSTM cell (tid<512)
__global__ __launch_bounds__(1024) void decoder_loop(LoopArgs A) {
    const int bid = blockIdx.x;
    const int tid = threadIdx.x;
    const int lane = tid & 63, wv = tid >> 6;
    const int ln = lane & 15, quad = lane >> 4;

    __shared__ __align__(16) union {
        struct { float cpart[16][512]; float es2[256]; float m2s[16]; float zs[16]; } B;
        float gt[64][36];
    } sm;

    unsigned* flags = A.flags;
    unsigned bt = 0;

    // phase A constants (active iff bid < 128, tid < 256)
    const int a_m0 = (bid >> 5) * 64, a_n0 = (bid & 31) * 16;
    // phase B constants
    const float4* vp = (const float4*)(A.vd + lane * 8);
    float4 vv0 = vp[0], vv1 = vp[1];
    float vr[8] = {vv0.x, vv0.y, vv0.z, vv0.w, vv1.x, vv1.y, vv1.z, vv1.w};
    const h8* ub0 = (const h8*)(A.CB + ((size_t)bid * 256 + wv * 16) * 1024) + lane;
    // phase C constants (active iff tid < 512)
    const int c_mt = wv & 3, c_nt = (wv >> 2) & 1;
    const int c_m0 = (bid & 3) * 64, c_by = bid >> 2;
    const int c_n0 = c_by * 32, c_p0 = c_by * 8;
    const float c_bs = A.bsum[c_n0 + c_nt * 16 + ln];
    const int c_ml = tid >> 3, c_pl = tid & 7;

#pragma unroll 1
    for (int t = 0; t < 256; ++t) {
        _Float16* qcur = (t & 1) ? A.qB : A.qA;
        _Float16* qnxt = (t & 1) ? A.qA : A.qB;

        // ---- phase A: wq2 = 2log2e * ds(256x1024) @ Wdh(512x1024)^T
        if (bid < 128 && tid < 256) {
            f4 acc = {0.f, 0.f, 0.f, 0.f};
            const h8* ap = (const h8*)(A.ds  + (size_t)(a_m0 + wv * 16 + ln) * 1024) + quad;
            const h8* bp = (const h8*)(A.Wdh + (size_t)(a_n0 + ln) * 1024) + quad;
#pragma unroll 8
            for (int k = 0; k < 32; ++k)
                acc = __builtin_amdgcn_mfma_f32_16x16x32_f16(ap[k * 4], bp[k * 4], acc, 0, 0, 0);
#pragma unroll
            for (int r = 0; r < 4; ++r)
                A.wq2[(size_t)(a_m0 + wv * 16 + quad * 4 + r) * 512 + a_n0 + ln] =
                    acc[r] * SC2LOG2E;
        }
        gbar(flags, ++bt);

        // ---- phase B: fused online-softmax attention for batch b = bid
        {
            const float4* wqp = (const float4*)(A.wq2 + (size_t)bid * 512 + lane * 8);
            float4 w0 = wqp[0], w1 = wqp[1];
            float wr[8] = {w0.x, w0.y, w0.z, w0.w, w1.x, w1.y, w1.z, w1.w};

            float m2 = -1e30f, Z = 0.f;
            float ch[8] = {0.f, 0.f, 0.f, 0.f, 0.f, 0.f, 0.f, 0.f};
#pragma unroll 4
            for (int i = 0; i < 16; ++i) {
                h8 u  = ub0[(size_t)i * 128];        // UH2 half (row stride 1024 f16)
                h8 hv = ub0[(size_t)i * 128 + 64];   // Hh half (same 2KB row)
                float acc = 0.0f;
#pragma unroll
                for (int j = 0; j < 8; ++j) {
                    float zz = wr[j] + (float)u[j];
                    acc = fmaf(vr[j], v_rcp(1.0f + v_exp2(zz)), acc);
                }
#pragma unroll
                for (int o = 32; o; o >>= 1) acc += __shfl_xor(acc, o, 64);
                float e2 = -SC2LOG2E * acc;          // exp2-domain score
                if (lane == 0) sm.B.es2[wv * 16 + i] = e2;
                if (e2 > m2) {
                    float s = v_exp2(m2 - e2);
                    Z *= s;
#pragma unroll
                    for (int k2 = 0; k2 < 8; ++k2) ch[k2] *= s;
                    m2 = e2;
                }
                float w = v_exp2(e2 - m2);
                Z += w;
#pragma unroll
                for (int k2 = 0; k2 < 8; ++k2) ch[k2] = fmaf(w, (float)hv[k2], ch[k2]);
            }
            *(float4*)&sm.B.cpart[wv][lane * 8]     = make_float4(ch[0], ch[1], ch[2], ch[3]);
            *(float4*)&sm.B.cpart[wv][lane * 8 + 4] = make_float4(ch[4], ch[5], ch[6], ch[7]);
            if (lane == 0) { sm.B.m2s[wv] = m2; sm.B.zs[wv] = Z; }
            __syncthreads();

            if (tid < 512) {
                float m2g = sm.B.m2s[0];
#pragma unroll
                for (int w2 = 1; w2 < 16; ++w2) m2g = fmaxf(m2g, sm.B.m2s[w2]);
                float Zg = 0.f, cg = 0.f;
#pragma unroll
                for (int w2 = 0; w2 < 16; ++w2) {
                    float f = v_exp2(sm.B.m2s[w2] - m2g);
                    Zg = fmaf(sm.B.zs[w2], f, Zg);
                    cg = fmaf(sm.B.cpart[w2][tid], f, cg);
                }
                float rz = v_rcp(Zg);
                float cval = cg * rz;
                qcur[(size_t)bid * 1024 + tid] = (_Float16)cval;
                if (t == 255) A.out[(size_t)bid * 1024 + 512 + tid] = cval;
                if (tid < 256) {
                    float beta = v_exp2(sm.B.es2[tid] - m2g) * rz;
                    __builtin_nontemporal_store(beta,
                        A.attn + (size_t)bid * 65536 + (size_t)t * 256 + tid);
                }
            }
        }
        gbar(flags, ++bt);

        // ---- phase C: gates = qcur @ Wg^T + bsum ; fused LSTM cell
        {
            bool act = (tid < 512);
            if (act) {
                f4 acc = {0.f, 0.f, 0.f, 0.f};
                const h8* ap = (const h8*)(qcur + (size_t)(c_m0 + c_mt * 16 + ln) * 1024) + quad;
                const h8* bp = (const h8*)(A.Wg + (size_t)(c_n0 + c_nt * 16 + ln) * 1024) + quad;
#pragma unroll 8
                for (int k = 0; k < 32; ++k)
                    acc = __builtin_amdgcn_mfma_f32_16x16x32_f16(ap[k * 4], bp[k * 4], acc, 0, 0, 0);
#pragma unroll
                for (int r = 0; r < 4; ++r)
                    sm.gt[c_mt * 16 + quad * 4 + r][c_nt * 16 + ln] = acc[r] + c_bs;
            }
            __syncthreads();
            if (act) {
                float4 g4 = *(const float4*)&sm.gt[c_ml][c_pl * 4];
                int b = c_m0 + c_ml, p = c_p0 + c_pl;
                float ig = fast_sigmoid(g4.x);
                float fg = fast_sigmoid(g4.y);
                float gg = fast_tanh(g4.z);
                float og = fast_sigmoid(g4.w);
                float sold = A.sbuf[(size_t)b * 512 + p];
                float snew = fmaf(fg, sold, ig * gg);
                float dnew = og * fast_tanh(snew);
                A.sbuf[(size_t)b * 512 + p] = snew;
                qnxt[(size_t)b * 1024 + 512 + p] = (_Float16)dnew;
                A.ds[(size_t)b * 1024 + p]       = (_Float16)dnew;
                A.ds[(size_t)b * 1024 + 512 + p] = (_Float16)snew;
                if (t == 255) A.out[(size_t)b * 1024 + p] = dnew;
            }
        }
        gbar(flags, ++bt);
    }
}

// ---------------------------------------------------------------------------
extern "C" void kernel_launch(void* const* d_in, const int* in_sizes, int n_in,
                              void* d_out, int out_size, void* d_ws, size_t ws_size,
                              hipStream_t stream) {
    const float* H   = (const float*)d_in[0];
    const float* d0  = (const float*)d_in[1];
    const float* s0  = (const float*)d_in[2];
    const float* Wd  = (const float*)d_in[3];
    const float* Ud  = (const float*)d_in[4];
    const float* vd  = (const float*)d_in[5];
    const float* Wih = (const float*)d_in[6];
    const float* Whh = (const float*)d_in[7];
    const float* bih = (const float*)d_in[8];
    const float* bhh = (const float*)d_in[9];

    float* out  = (float*)d_out;            // [B,1,1024]
    float* attn = out + 262144;             // [B,T,T]

    char* ws = (char*)d_ws;
    size_t off = 0;
    _Float16* CB   = (_Float16*)(ws + off); off += 134217728;   // 65536 rows x 1024 f16
    _Float16* Wdh  = (_Float16*)(ws + off); off += 1048576;
    _Float16* Wg   = (_Float16*)(ws + off); off += 4194304;
    float*    bsum = (float*)   (ws + off); off += 8192;
    float*    wq2  = (float*)   (ws + off); off += 524288;
    _Float16* qA   = (_Float16*)(ws + off); off += 524288;
    _Float16* qB   = (_Float16*)(ws + off); off += 524288;
    _Float16* ds   = (_Float16*)(ws + off); off += 524288;
    float*    sbuf = (float*)   (ws + off); off += 524288;
    unsigned* bar  = (unsigned*)(ws + off); off += 4096;

    convert_f16<<<512, 256, 0, stream>>>(Wd, Wdh, 524288);
    build_wg<<<2048, 256, 0, stream>>>(Wih, Whh, Wg);
    build_bsum<<<8, 256, 0, stream>>>(bih, bhh, bsum);
    convert_cb<<<32768, 256, 0, stream>>>(H, CB);
    init_state<<<512, 256, 0, stream>>>(d0, s0, sbuf, qA, ds);
    zero_bar<<<4, 256, 0, stream>>>(bar, 1024);
    uh_mfma<<<dim3(1024, 16), 128, 0, stream>>>(H, Ud, CB);

    LoopArgs la;
    la.CB = CB; la.Wdh = Wdh; la.Wg = Wg; la.bsum = bsum; la.vd = vd;
    la.wq2 = wq2; la.qA = qA; la.qB = qB; la.ds = ds; la.sbuf = sbuf;
    la.out = out; la.attn = attn; la.flags = bar;
    void* kp[] = { &la };
    if (hipLaunchCooperativeKernel((void*)decoder_loop, dim3(256), dim3(1024),
                                   kp, 0, stream) != hipSuccess) {
        decoder_loop<<<dim3(256), dim3(1024), 0, stream>>>(la);
    }
}

// Round 4
// 16221.872 us; speedup vs baseline: 2.4214x; 2.4214x over previous
//
#include <hip/hip_runtime.h>
#include <hip/hip_fp16.h>

// Problem constants: B=256, T=256, M=512, P=512
typedef _Float16 h4 __attribute__((ext_vector_type(4)));
typedef _Float16 h8 __attribute__((ext_vector_type(8)));
typedef float    f4 __attribute__((ext_vector_type(4)));

#define SC2LOG2E 2.8853900817779268f   // 2 * log2(e)

__device__ __forceinline__ float v_exp2(float x) { float r; asm("v_exp_f32 %0, %1" : "=v"(r) : "v"(x)); return r; }
__device__ __forceinline__ float v_rcp (float x) { float r; asm("v_rcp_f32 %0, %1" : "=v"(r) : "v"(x)); return r; }
__device__ __forceinline__ float fast_tanh(float x) {
    float e = __expf(2.0f * x);
    return 1.0f - 2.0f * v_rcp(e + 1.0f);
}
__device__ __forceinline__ float fast_sigmoid(float x) {
    return v_rcp(1.0f + __expf(-x));
}

// ---- device-coherent (LLC, bypass non-coherent per-XCD L2) payload access --
__device__ __forceinline__ h8 ld_h8_dc(const _Float16* p) {
    h8 r;
    asm volatile("global_load_dwordx4 %0, %1, off sc0 sc1" : "=v"(r) : "v"(p));
    return r;
}
__device__ __forceinline__ f4 ld_f4_dc(const float* p) {
    f4 r;
    asm volatile("global_load_dwordx4 %0, %1, off sc0 sc1" : "=v"(r) : "v"(p));
    return r;
}
__device__ __forceinline__ void st_f_dc(float* p, float v) {
    asm volatile("global_store_dword %0, %1, off sc0 sc1" :: "v"(p), "v"(v) : "memory");
}
__device__ __forceinline__ void st_h_dc(_Float16* p, _Float16 v) {
    unsigned u = (unsigned)__builtin_bit_cast(unsigned short, v);
    asm volatile("global_store_short %0, %1, off sc0 sc1" :: "v"(p), "v"(u) : "memory");
}

// ---------------------------------------------------------------------------
__global__ void convert_f16(const float* __restrict__ s, _Float16* __restrict__ d, int n) {
    int i = (blockIdx.x * 256 + threadIdx.x) * 4;
    if (i < n) {
        float4 v = *(const float4*)(s + i);
        h4 o = {(_Float16)v.x, (_Float16)v.y, (_Float16)v.z, (_Float16)v.w};
        *(h4*)(d + i) = o;
    }
}

// H f32 -> Hh half of combined buffer: CB row r (stride 1024 f16) = [UH2|Hh]
__global__ void convert_cb(const float* __restrict__ H, _Float16* __restrict__ CB) {
    int i = (blockIdx.x * 256 + threadIdx.x) * 4;   // over 33554432
    int r = i >> 9, m = i & 511;
    float4 v = *(const float4*)(H + i);
    h4 o = {(_Float16)v.x, (_Float16)v.y, (_Float16)v.z, (_Float16)v.w};
    *(h4*)(CB + (size_t)r * 1024 + 512 + m) = o;
}

// ---------------------------------------------------------------------------
__global__ void build_wg(const float* __restrict__ Wih, const float* __restrict__ Whh,
                         _Float16* __restrict__ Wg) {
    int idx = (blockIdx.x * 256 + threadIdx.x) * 4;    // over 2048*1024
    int np = idx >> 10, k = idx & 1023;
    int p = np >> 2, g = np & 3, row = g * 512 + p;
    const float* src = (k < 512) ? Wih + (size_t)row * 512 + k
                                 : Whh + (size_t)row * 512 + (k - 512);
    float4 v = *(const float4*)src;
    h4 o = {(_Float16)v.x, (_Float16)v.y, (_Float16)v.z, (_Float16)v.w};
    *(h4*)(Wg + idx) = o;
}

__global__ void build_bsum(const float* __restrict__ bih, const float* __restrict__ bhh,
                           float* __restrict__ bsum) {
    int np = blockIdx.x * 256 + threadIdx.x;  // 2048
    int p = np >> 2, g = np & 3, row = g * 512 + p;
    bsum[np] = bih[row] + bhh[row];
}

// ---------------------------------------------------------------------------
__global__ void init_state(const float* __restrict__ d0, const float* __restrict__ s0,
                           _Float16* __restrict__ qA, _Float16* __restrict__ ds) {
    int i = blockIdx.x * 256 + threadIdx.x;   // 512 x 256 = 131072
    float dv = d0[i], sv = s0[i];
    int b = i >> 9, j = i & 511;
    qA[(size_t)b * 1024 + 512 + j] = (_Float16)dv;
    ds[(size_t)b * 1024 + j]       = (_Float16)dv;
    ds[(size_t)b * 1024 + 512 + j] = (_Float16)sv;
}

__global__ void zero_bar(unsigned* __restrict__ bar, int n) {
    int i = blockIdx.x * 256 + threadIdx.x;
    if (i < n) bar[i] = 0u;
}

// ---------------------------------------------------------------------------
// CB[r][n] (n<512, row stride 1024) = f16( 2log2e * sum_k H[r,k]*Ud[n,k] ).
__global__ __launch_bounds__(128) void uh_mfma(const float* __restrict__ H,
                                               const float* __restrict__ Ud,
                                               _Float16* __restrict__ CB) {
    int tid = threadIdx.x;
    int lane = tid & 63, w = tid >> 6;
    int ln = lane & 15, quad = lane >> 4;
    int m0 = blockIdx.x * 64, n0 = blockIdx.y * 32;
    f4 z = {0.f, 0.f, 0.f, 0.f};
    f4 acc[4] = {z, z, z, z};
    const float* brow = Ud + (size_t)(n0 + w * 16 + ln) * 512 + quad * 8;
    const float* arow = H  + (size_t)(m0 + ln) * 512 + quad * 8;
#pragma unroll 2
    for (int k = 0; k < 16; k++) {
        float4 bx = *(const float4*)(brow + k * 32);
        float4 by = *(const float4*)(brow + k * 32 + 4);
        h8 b = {(_Float16)bx.x, (_Float16)bx.y, (_Float16)bx.z, (_Float16)bx.w,
                (_Float16)by.x, (_Float16)by.y, (_Float16)by.z, (_Float16)by.w};
#pragma unroll
        for (int mt = 0; mt < 4; mt++) {
            const float* ap = arow + (size_t)mt * 16 * 512 + k * 32;
            float4 ax = *(const float4*)ap;
            float4 ay = *(const float4*)(ap + 4);
            h8 a = {(_Float16)ax.x, (_Float16)ax.y, (_Float16)ax.z, (_Float16)ax.w,
                    (_Float16)ay.x, (_Float16)ay.y, (_Float16)ay.z, (_Float16)ay.w};
            acc[mt] = __builtin_amdgcn_mfma_f32_16x16x32_f16(a, b, acc[mt], 0, 0, 0);
        }
    }
#pragma unroll
    for (int mt = 0; mt < 4; mt++)
#pragma unroll
        for (int r = 0; r < 4; r++)
            CB[(size_t)(m0 + mt * 16 + quad * 4 + r) * 1024 + n0 + w * 16 + ln] =
                (_Float16)(acc[mt][r] * SC2LOG2E);
}

// ---------------------------------------------------------------------------
// Fence-free central-collector grid barrier. Correctness: __syncthreads drains
// vmcnt(0) for every thread before s_barrier (compiler-guaranteed), so all
// payload stores (which are sc0/sc1 device-coherent) are LLC-visible before
// the arrival flag is stored. Readers access payload with sc0/sc1 loads that
// bypass the (possibly stale) per-XCD L2 -> no acquire invalidate needed.
__device__ __forceinline__ void gbar(unsigned* __restrict__ arrive,
                                     unsigned* __restrict__ gen,
                                     unsigned ticket) {
    __syncthreads();
    if (blockIdx.x == 0) {
        int tid = threadIdx.x;
        if (tid >= 1 && tid < 256) {
            while (__hip_atomic_load(arrive + (size_t)tid * 16, __ATOMIC_RELAXED,
                                     __HIP_MEMORY_SCOPE_AGENT) < ticket)
                __builtin_amdgcn_s_sleep(2);
        }
        __syncthreads();
        if (tid == 0)
            __hip_atomic_store(gen, ticket, __ATOMIC_RELAXED, __HIP_MEMORY_SCOPE_AGENT);
    } else {
        if (threadIdx.x == 0) {
            __hip_atomic_store(arrive + (size_t)blockIdx.x * 16, ticket,
                               __ATOMIC_RELAXED, __HIP_MEMORY_SCOPE_AGENT);
            while (__hip_atomic_load(gen, __ATOMIC_RELAXED,
                                     __HIP_MEMORY_SCOPE_AGENT) < ticket)
                __builtin_amdgcn_s_sleep(2);
        }
        __syncthreads();
    }
}

// ---------------------------------------------------------------------------
struct LoopArgs {
    const _Float16* CB;    // [65536][1024] f16: [.,0:512]=UH2*2log2e, [.,512:1024]=Hh
    const _Float16* Wdh;
    const _Float16* Wg;
    const float*    bsum;
    const float*    vd;
    const float*    s0;
    float*          wq2;   // payload (dc access only)
    _Float16*       qA;    // payload
    _Float16*       qB;    // payload
    _Float16*       ds;    // payload
    float*          out;
    float*          attn;
    unsigned*       bar;   // arrive[256*16], gen at +4096
};

// Persistent fused t-loop: 256 blocks x 1024 threads (16 waves).
__global__ __launch_bounds__(1024) void decoder_loop(LoopArgs A) {
    const int bid = blockIdx.x;
    const int tid = threadIdx.x;
    const int lane = tid & 63, wv = tid >> 6;
    const int ln = lane & 15, quad = lane >> 4;

    __shared__ __align__(16) union {
        struct { float cpart[16][512]; float es2[256]; float m2s[16]; float zs[16]; } B;
        float gt[64][36];
    } sm;

    unsigned* arrive = A.bar;
    unsigned* gen    = A.bar + 4096;
    unsigned  bt     = 0;

    // phase A constants (active iff bid < 128, tid < 256)
    const int a_m0 = (bid >> 5) * 64, a_n0 = (bid & 31) * 16;
    // phase B constants
    const float4* vp = (const float4*)(A.vd + lane * 8);
    float4 vv0 = vp[0], vv1 = vp[1];
    float vr[8] = {vv0.x, vv0.y, vv0.z, vv0.w, vv1.x, vv1.y, vv1.z, vv1.w};
    const h8* ub0 = (const h8*)(A.CB + ((size_t)bid * 256 + wv * 16) * 1024) + lane;
    // phase C constants (active iff tid < 512)
    const int c_mt = wv & 3, c_nt = (wv >> 2) & 1;
    const int c_m0 = (bid & 3) * 64, c_by = bid >> 2;
    const int c_n0 = c_by * 32, c_p0 = c_by * 8;
    const float c_bs = A.bsum[c_n0 + c_nt * 16 + ln];
    const int c_ml = tid >> 3, c_pl = tid & 7;
    const int c_b = c_m0 + c_ml, c_p = c_p0 + c_pl;
    // LSTM cell state lives in a register: this thread owns (c_b, c_p) forever.
    float s_state = (tid < 512) ? A.s0[(size_t)c_b * 512 + c_p] : 0.f;

#pragma unroll 1
    for (int t = 0; t < 256; ++t) {
        _Float16* qcur = (t & 1) ? A.qB : A.qA;
        _Float16* qnxt = (t & 1) ? A.qA : A.qB;

        // ---- phase A: wq2 = 2log2e * ds(256x1024) @ Wdh(512x1024)^T
        if (bid < 128 && tid < 256) {
            f4 acc = {0.f, 0.f, 0.f, 0.f};
            const h8* ap = (const h8*)(A.ds  + (size_t)(a_m0 + wv * 16 + ln) * 1024) + quad;
            const h8* bp = (const h8*)(A.Wdh + (size_t)(a_n0 + ln) * 1024) + quad;
#pragma unroll
            for (int kc = 0; kc < 4; ++kc) {
                h8 areg[8];
#pragma unroll
                for (int u = 0; u < 8; ++u)
                    areg[u] = ld_h8_dc((const _Float16*)(ap + (kc * 8 + u) * 4));
                asm volatile("s_waitcnt vmcnt(0)" ::: "memory");
                __builtin_amdgcn_sched_barrier(0);
#pragma unroll
                for (int u = 0; u < 8; ++u)
                    acc = __builtin_amdgcn_mfma_f32_16x16x32_f16(areg[u], bp[(kc * 8 + u) * 4],
                                                                 acc, 0, 0, 0);
            }
#pragma unroll
            for (int r = 0; r < 4; ++r)
                st_f_dc(A.wq2 + (size_t)(a_m0 + wv * 16 + quad * 4 + r) * 512 + a_n0 + ln,
                        acc[r] * SC2LOG2E);
        }
        gbar(arrive, gen, ++bt);

        // ---- phase B: fused online-softmax attention for batch b = bid
        {
            f4 w0 = ld_f4_dc(A.wq2 + (size_t)bid * 512 + lane * 8);
            f4 w1 = ld_f4_dc(A.wq2 + (size_t)bid * 512 + lane * 8 + 4);
            asm volatile("s_waitcnt vmcnt(0)" ::: "memory");
            __builtin_amdgcn_sched_barrier(0);
            float wr[8] = {w0[0], w0[1], w0[2], w0[3], w1[0], w1[1], w1[2], w1[3]};

            float m2 = -1e30f, Z = 0.f;
            float ch[8] = {0.f, 0.f, 0.f, 0.f, 0.f, 0.f, 0.f, 0.f};
#pragma unroll 4
            for (int i = 0; i < 16; ++i) {
                h8 u  = ub0[(size_t)i * 128];        // UH2 half (ordinary load, L2-cached)
                h8 hv = ub0[(size_t)i * 128 + 64];   // Hh half (same 2KB row)
                float acc = 0.0f;
#pragma unroll
                for (int j = 0; j < 8; ++j) {
                    float zz = wr[j] + (float)u[j];
                    acc = fmaf(vr[j], v_rcp(1.0f + v_exp2(zz)), acc);
                }
#pragma unroll
                for (int o = 32; o; o >>= 1) acc += __shfl_xor(acc, o, 64);
                float e2 = -SC2LOG2E * acc;          // exp2-domain score
                if (lane == 0) sm.B.es2[wv * 16 + i] = e2;
                if (e2 > m2) {
                    float s = v_exp2(m2 - e2);
                    Z *= s;
#pragma unroll
                    for (int k2 = 0; k2 < 8; ++k2) ch[k2] *= s;
                    m2 = e2;
                }
                float w = v_exp2(e2 - m2);
                Z += w;
#pragma unroll
                for (int k2 = 0; k2 < 8; ++k2) ch[k2] = fmaf(w, (float)hv[k2], ch[k2]);
            }
            *(float4*)&sm.B.cpart[wv][lane * 8]     = make_float4(ch[0], ch[1], ch[2], ch[3]);
            *(float4*)&sm.B.cpart[wv][lane * 8 + 4] = make_float4(ch[4], ch[5], ch[6], ch[7]);
            if (lane == 0) { sm.B.m2s[wv] = m2; sm.B.zs[wv] = Z; }
            __syncthreads();

            if (tid < 512) {
                float m2g = sm.B.m2s[0];
#pragma unroll
                for (int w2 = 1; w2 < 16; ++w2) m2g = fmaxf(m2g, sm.B.m2s[w2]);
                float Zg = 0.f, cg = 0.f;
#pragma unroll
                for (int w2 = 0; w2 < 16; ++w2) {
                    float f = v_exp2(sm.B.m2s[w2] - m2g);
                    Zg = fmaf(sm.B.zs[w2], f, Zg);
                    cg = fmaf(sm.B.cpart[w2][tid], f, cg);
                }
                float rz = v_rcp(Zg);
                float cval = cg * rz;
                st_h_dc(qcur + (size_t)bid * 1024 + tid, (_Float16)cval);
                if (t == 255) A.out[(size_t)bid * 1024 + 512 + tid] = cval;
                if (tid < 256) {
                    float beta = v_exp2(sm.B.es2[tid] - m2g) * rz;
                    __builtin_nontemporal_store(beta,
                        A.attn + (size_t)bid * 65536 + (size_t)t * 256 + tid);
                }
            }
        }
        gbar(arrive, gen, ++bt);

        // ---- phase C: gates = qcur @ Wg^T + bsum ; fused LSTM cell
        {
            bool act = (tid < 512);
            if (act) {
                f4 acc = {0.f, 0.f, 0.f, 0.f};
                const h8* ap = (const h8*)(qcur + (size_t)(c_m0 + c_mt * 16 + ln) * 1024) + quad;
                const h8* bp = (const h8*)(A.Wg + (size_t)(c_n0 + c_nt * 16 + ln) * 1024) + quad;
#pragma unroll
                for (int kc = 0; kc < 4; ++kc) {
                    h8 areg[8];
#pragma unroll
                    for (int u = 0; u < 8; ++u)
                        areg[u] = ld_h8_dc((const _Float16*)(ap + (kc * 8 + u) * 4));
                    asm volatile("s_waitcnt vmcnt(0)" ::: "memory");
                    __builtin_amdgcn_sched_barrier(0);
#pragma unroll
                    for (int u = 0; u < 8; ++u)
                        acc = __builtin_amdgcn_mfma_f32_16x16x32_f16(areg[u], bp[(kc * 8 + u) * 4],
                                                                     acc, 0, 0, 0);
                }
#pragma unroll
                for (int r = 0; r < 4; ++r)
                    sm.gt[c_mt * 16 + quad * 4 + r][c_nt * 16 + ln] = acc[r] + c_bs;
            }
            __syncthreads();
            if (act) {
                float4 g4 = *(const float4*)&sm.gt[c_ml][c_pl * 4];
                float ig = fast_sigmoid(g4.x);
                float fg = fast_sigmoid(g4.y);
                float gg = fast_tanh(g4.z);
                float og = fast_sigmoid(g4.w);
                float snew = fmaf(fg, s_state, ig * gg);
                float dnew = og * fast_tanh(snew);
                s_state = snew;
                st_h_dc(qnxt + (size_t)c_b * 1024 + 512 + c_p, (_Float16)dnew);
                st_h_dc(A.ds + (size_t)c_b * 1024 + c_p,       (_Float16)dnew);
                st_h_dc(A.ds + (size_t)c_b * 1024 + 512 + c_p, (_Float16)snew);
                if (t == 255) A.out[(size_t)c_b * 1024 + c_p] = dnew;
            }
        }
        gbar(arrive, gen, ++bt);
    }
}

// ---------------------------------------------------------------------------
extern "C" void kernel_launch(void* const* d_in, const int* in_sizes, int n_in,
                              void* d_out, int out_size, void* d_ws, size_t ws_size,
                              hipStream_t stream) {
    const float* H   = (const float*)d_in[0];
    const float* d0  = (const float*)d_in[1];
    const float* s0  = (const float*)d_in[2];
    const float* Wd  = (const float*)d_in[3];
    const float* Ud  = (const float*)d_in[4];
    const float* vd  = (const float*)d_in[5];
    const float* Wih = (const float*)d_in[6];
    const float* Whh = (const float*)d_in[7];
    const float* bih = (const float*)d_in[8];
    const float* bhh = (const float*)d_in[9];

    float* out  = (float*)d_out;            // [B,1,1024]
    float* attn = out + 262144;             // [B,T,T]

    char* ws = (char*)d_ws;
    size_t off = 0;
    _Float16* CB   = (_Float16*)(ws + off); off += 134217728;   // 65536 rows x 1024 f16
    _Float16* Wdh  = (_Float16*)(ws + off); off += 1048576;
    _Float16* Wg   = (_Float16*)(ws + off); off += 4194304;
    float*    bsum = (float*)   (ws + off); off += 8192;
    float*    wq2  = (float*)   (ws + off); off += 524288;
    _Float16* qA   = (_Float16*)(ws + off); off += 524288;
    _Float16* qB   = (_Float16*)(ws + off); off += 524288;
    _Float16* ds   = (_Float16*)(ws + off); off += 524288;
    unsigned* bar  = (unsigned*)(ws + off); off += 32768;

    convert_f16<<<512, 256, 0, stream>>>(Wd, Wdh, 524288);
    build_wg<<<2048, 256, 0, stream>>>(Wih, Whh, Wg);
    build_bsum<<<8, 256, 0, stream>>>(bih, bhh, bsum);
    convert_cb<<<32768, 256, 0, stream>>>(H, CB);
    init_state<<<512, 256, 0, stream>>>(d0, s0, qA, ds);
    zero_bar<<<17, 256, 0, stream>>>(bar, 4097);
    uh_mfma<<<dim3(1024, 16), 128, 0, stream>>>(H, Ud, CB);

    LoopArgs la;
    la.CB = CB; la.Wdh = Wdh; la.Wg = Wg; la.bsum = bsum; la.vd = vd; la.s0 = s0;
    la.wq2 = wq2; la.qA = qA; la.qB = qB; la.ds = ds;
    la.out = out; la.attn = attn; la.bar = bar;
    void* kp[] = { &la };
    if (hipLaunchCooperativeKernel((void*)decoder_loop, dim3(256), dim3(1024),
                                   kp, 0, stream) != hipSuccess) {
        decoder_loop<<<dim3(256), dim3(1024), 0, stream>>>(la);
    }
}